// Round 10
// baseline (682.518 us; speedup 1.0000x reference)
//
#include <hip/hip_runtime.h>
#include <cfloat>
#include <math.h>

#define NEG_SLOPE 0.2f

typedef short short8 __attribute__((ext_vector_type(8)));
typedef short short4v __attribute__((ext_vector_type(4)));
typedef float f32x4 __attribute__((ext_vector_type(4)));

__device__ __forceinline__ short f2bf(float x) {
    unsigned u = __float_as_uint(x);
    u += 0x7fffu + ((u >> 16) & 1u);
    return (short)(u >> 16);
}
__device__ __forceinline__ float bf2f(unsigned short s) {
    return __uint_as_float((unsigned)s << 16);
}

// wave-local LDS fence (buffers are wave-private; no block barrier needed)
__device__ __forceinline__ void lds_fence() {
    __asm__ __volatile__("s_waitcnt lgkmcnt(0)" ::: "memory");
}

// ---------------- CSR construction ----------------

__global__ void count_deg_k(const int* __restrict__ dst, int* __restrict__ deg,
                            int* __restrict__ rank, int E) {
    int i = blockIdx.x * 256 + threadIdx.x;
    if (i < E) rank[i] = atomicAdd(&deg[dst[i]], 1);
}

// parallel scan: A) 4096 chunk sums  B) scan chunk sums  C) write offsets
__global__ void scanA_k(const int* __restrict__ deg, int* __restrict__ csum, int n) {
    int t = blockIdx.x * 256 + threadIdx.x;   // t < 4096
    int ch = (n + 4095) >> 12;
    int beg = t * ch, end = min(beg + ch, n);
    int s = 0;
    for (int i = beg; i < end; ++i) s += deg[i];
    csum[t] = s;
}

__global__ void scanB_k(int* __restrict__ csum) {
    __shared__ int part[1024];
    int tid = threadIdx.x;
    int c[4];
    int s = 0;
#pragma unroll
    for (int i = 0; i < 4; ++i) { c[i] = csum[tid * 4 + i]; s += c[i]; }
    part[tid] = s;
    __syncthreads();
    for (int d = 1; d < 1024; d <<= 1) {
        int v = (tid >= d) ? part[tid - d] : 0;
        __syncthreads();
        part[tid] += v;
        __syncthreads();
    }
    int base = (tid > 0) ? part[tid - 1] : 0;
#pragma unroll
    for (int i = 0; i < 4; ++i) { csum[tid * 4 + i] = base; base += c[i]; }
}

__global__ void scanC_k(const int* __restrict__ deg, const int* __restrict__ csum,
                        int* __restrict__ off, int n, int E) {
    int t = blockIdx.x * 256 + threadIdx.x;   // t < 4096
    int ch = (n + 4095) >> 12;
    int beg = t * ch, end = min(beg + ch, n);
    int run = csum[t];
    for (int i = beg; i < end; ++i) { off[i] = run; run += deg[i]; }
    if (t == 0) off[n] = E;
}

__global__ void scatter_k(const int* __restrict__ src, const int* __restrict__ dst,
                          const int* __restrict__ off, const int* __restrict__ rank,
                          int* __restrict__ srcp, int E) {
    int i = blockIdx.x * 256 + threadIdx.x;
    if (i >= E) return;
    srcp[off[dst[i]] + rank[i]] = src[i];
}

// ---------------- bf16 weight precompute: BT[n*K+k] = B[k*OUT+n] ----------------

__global__ void conv_w_k(const float* W0, const float* W1, const float* Wr1,
                         const float* W2, const float* Wr2, const float* Wc1,
                         const float* We, const float* Wc2,
                         short* W0T, short* W1T, short* Wr1T, short* W2T, short* Wr2T,
                         short* Wc1aT, short* Wc1bT, short* WeT, short* Wc1T, short* Wc2T) {
    int t = blockIdx.x * 256 + threadIdx.x;
    const float* src; short* dst; int K, OUT, base;
    if      (t < 16384) { src = W0;            dst = W0T;   K = 128; OUT = 128; base = 0; }
    else if (t < 24576) { src = W1;            dst = W1T;   K = 128; OUT = 64;  base = 16384; }
    else if (t < 32768) { src = Wr1;           dst = Wr1T;  K = 128; OUT = 64;  base = 24576; }
    else if (t < 34816) { src = W2;            dst = W2T;   K = 64;  OUT = 32;  base = 32768; }
    else if (t < 36864) { src = Wr2;           dst = Wr2T;  K = 64;  OUT = 32;  base = 34816; }
    else if (t < 37888) { src = Wc1;           dst = Wc1aT; K = 32;  OUT = 32;  base = 36864; }
    else if (t < 38912) { src = Wc1 + 1024;    dst = Wc1bT; K = 32;  OUT = 32;  base = 37888; }
    else if (t < 47104) { src = We;            dst = WeT;   K = 64;  OUT = 128; base = 38912; }
    else if (t < 51200) { src = Wc1 + 64 * 32; dst = Wc1T;  K = 128; OUT = 32;  base = 47104; }
    else if (t < 51712) { src = Wc2;           dst = Wc2T;  K = 32;  OUT = 16;  base = 51200; }
    else return;
    int local = t - base;
    int k = local / OUT, n = local % OUT;
    dst[n * K + k] = f2bf(src[k * OUT + n]);
}

// ---------------- per-wave MFMA GEMM: 16 rows/wave, dual fused outputs ----------------

template<int K, int NT1, int NT2, bool C1B16, bool AF32>
__global__ __launch_bounds__(256) void gemmM_k(const void* __restrict__ A,
                                               const short* __restrict__ B1T, void* __restrict__ C1,
                                               const short* __restrict__ B2T, float* __restrict__ C2,
                                               int N) {
    int w = threadIdx.x >> 6, lane = threadIdx.x & 63;
    int tile = blockIdx.x * 4 + w;
    int row0 = tile * 16;
    if (row0 >= N) return;
    int m = lane & 15, q = lane >> 4;
    int arow = row0 + m; if (arow >= N) arow = N - 1;

    constexpr int KT = K / 32;
    short8 Af[KT];
    if constexpr (AF32) {
        const float* Ap = (const float*)A + (size_t)arow * K;
#pragma unroll
        for (int kt = 0; kt < KT; ++kt) {
            float4 x = *(const float4*)&Ap[kt * 32 + q * 8];
            float4 y = *(const float4*)&Ap[kt * 32 + q * 8 + 4];
            short8 s;
            s[0] = f2bf(x.x); s[1] = f2bf(x.y); s[2] = f2bf(x.z); s[3] = f2bf(x.w);
            s[4] = f2bf(y.x); s[5] = f2bf(y.y); s[6] = f2bf(y.z); s[7] = f2bf(y.w);
            Af[kt] = s;
        }
    } else {
        const short* Ap = (const short*)A + (size_t)arow * K;
#pragma unroll
        for (int kt = 0; kt < KT; ++kt)
            Af[kt] = *(const short8*)&Ap[kt * 32 + q * 8];
    }

#pragma unroll
    for (int nt = 0; nt < NT1; ++nt) {
        f32x4 acc = {0.f, 0.f, 0.f, 0.f};
#pragma unroll
        for (int kt = 0; kt < KT; ++kt) {
            short8 b = *(const short8*)&B1T[(size_t)(nt * 16 + m) * K + kt * 32 + q * 8];
            acc = __builtin_amdgcn_mfma_f32_16x16x32_bf16(Af[kt], b, acc, 0, 0, 0);
        }
#pragma unroll
        for (int r = 0; r < 4; ++r) {
            int row = row0 + q * 4 + r;
            if (row < N) {
                if constexpr (C1B16)
                    ((short*)C1)[(size_t)row * (NT1 * 16) + nt * 16 + m] = f2bf(acc[r]);
                else
                    ((float*)C1)[(size_t)row * (NT1 * 16) + nt * 16 + m] = acc[r];
            }
        }
    }
    if constexpr (NT2 > 0) {
#pragma unroll
        for (int nt = 0; nt < NT2; ++nt) {
            f32x4 acc = {0.f, 0.f, 0.f, 0.f};
#pragma unroll
            for (int kt = 0; kt < KT; ++kt) {
                short8 b = *(const short8*)&B2T[(size_t)(nt * 16 + m) * K + kt * 32 + q * 8];
                acc = __builtin_amdgcn_mfma_f32_16x16x32_bf16(Af[kt], b, acc, 0, 0, 0);
            }
#pragma unroll
            for (int r = 0; r < 4; ++r) {
                int row = row0 + q * 4 + r;
                if (row < N)
                    C2[(size_t)row * (NT2 * 16) + nt * 16 + m] = acc[r];
            }
        }
    }
}

// ---------------- attention logits (from bf16 feat) ----------------

template<int H, int D>
__global__ void elr_k(const short* __restrict__ featb, const float* __restrict__ al,
                      const float* __restrict__ ar, float* __restrict__ el,
                      float* __restrict__ er, int n) {
    int i = blockIdx.x * 256 + threadIdx.x;
    if (i >= n * H) return;
    int h = i % H;
    const short* f = featb + (size_t)(i / H) * (H * D) + h * D;
    float sl = 0.f, sr = 0.f;
#pragma unroll
    for (int d = 0; d < D; ++d) {
        float v = bf2f((unsigned short)f[d]);
        sl = fmaf(v, al[h * D + d], sl);
        sr = fmaf(v, ar[h * D + d], sr);
    }
    el[i] = sl; er[i] = sr;
}

// ---- GAT node stage: wave-per-node, single sweep, no-max softmax, staged bf16 gathers ----

template<int H, int D, bool ACT>
__global__ __launch_bounds__(256) void gat_node3_k(
    const int* __restrict__ off, const int* __restrict__ srcp,
    const float* __restrict__ el, const float* __restrict__ er,
    const short* __restrict__ featb,
    const float* __restrict__ res, const float* __restrict__ bias,
    const float* __restrict__ bg, const float* __restrict__ bb,
    const float* __restrict__ bm, const float* __restrict__ bv,
    short* __restrict__ houtb, int N) {
    constexpr int HD = H * D;
    constexpr bool PAIR = (HD > 64);
    constexpr int CH = 64 / H;
    constexpr int SB = (CH < 8) ? CH : 8;
    int wv_ = threadIdx.x >> 6;
    int lane = threadIdx.x & 63;
    int n = blockIdx.x * 4 + wv_;
    if (n >= N) return;
    int beg = off[n], end = off[n + 1];

    int hh = lane % H;
    int cc = lane / H;
    float ern = er[(size_t)n * H + hh];

    int k0 = PAIR ? 2 * lane : lane;
    int h0 = k0 / D; if (h0 > H - 1) h0 = H - 1;

    float acc0 = 0.f, acc1 = 0.f, svp = 0.f;

    for (int i0 = beg; i0 < end; i0 += CH) {
        int iw = i0 + cc;
        float wv = 0.f;
        int sidx = 0;
        if (iw < end) {
            sidx = srcp[iw];
            float x = el[(size_t)sidx * H + hh] + ern;
            x = x > 0.f ? x : NEG_SLOPE * x;
            wv = __expf(x);                  // no max-sub: |x| is O(1) by construction
        }
        svp += wv;
        int lim = min(end - i0, CH);
        for (int rb = 0; rb < lim; rb += SB) {
            int bs = lim - rb; if (bs > SB) bs = SB;
            float ws[SB]; int ss[SB];
#pragma unroll
            for (int j = 0; j < SB; ++j) {
                int sl = (rb + j) * H + h0;
                ws[j] = __shfl(wv, sl, 64);
                ss[j] = __shfl(sidx, sl, 64);
            }
            if constexpr (PAIR) {
                unsigned rows[SB];
#pragma unroll
                for (int j = 0; j < SB; ++j)
                    if (j < bs) rows[j] = *(const unsigned*)&featb[(size_t)ss[j] * HD + k0];
#pragma unroll
                for (int j = 0; j < SB; ++j)
                    if (j < bs) {
                        acc0 = fmaf(ws[j], bf2f((unsigned short)(rows[j] & 0xffffu)), acc0);
                        acc1 = fmaf(ws[j], bf2f((unsigned short)(rows[j] >> 16)), acc1);
                    }
            } else {
                unsigned short rows[SB];
#pragma unroll
                for (int j = 0; j < SB; ++j)
                    if (j < bs && lane < HD)
                        rows[j] = (unsigned short)featb[(size_t)ss[j] * HD + k0];
#pragma unroll
                for (int j = 0; j < SB; ++j)
                    if (j < bs && lane < HD)
                        acc0 = fmaf(ws[j], bf2f(rows[j]), acc0);
            }
        }
    }
#pragma unroll
    for (int mm = H; mm < 64; mm <<= 1) svp += __shfl_xor(svp, mm, 64);
    bool has_edges = end > beg;
    float inv0 = has_edges ? 1.f / __shfl(svp, h0, 64) : 0.f;

    if constexpr (PAIR) {
        float2 rs = *(const float2*)&res[(size_t)n * HD + k0];
        float2 bi = *(const float2*)&bias[k0];
        float2 gm = *(const float2*)&bm[k0];
        float2 gv = *(const float2*)&bv[k0];
        float2 gg = *(const float2*)&bg[k0];
        float2 gb = *(const float2*)&bb[k0];
        float x0 = acc0 * inv0 + rs.x + bi.x;
        float x1 = acc1 * inv0 + rs.y + bi.y;
        if (ACT) { x0 = x0 > 0.f ? x0 : expm1f(x0); x1 = x1 > 0.f ? x1 : expm1f(x1); }
        float o0 = (x0 - gm.x) * (gg.x * rsqrtf(gv.x + 1e-5f)) + gb.x;
        float o1 = (x1 - gm.y) * (gg.y * rsqrtf(gv.y + 1e-5f)) + gb.y;
        ushort2 hb;
        hb.x = (unsigned short)f2bf(o0);
        hb.y = (unsigned short)f2bf(o1);
        *(ushort2*)&houtb[(size_t)n * HD + k0] = hb;
    } else {
        if (lane < HD) {
            int k = k0;
            float x = acc0 * inv0 + res[(size_t)n * HD + k] + bias[k];
            if (ACT) x = x > 0.f ? x : expm1f(x);
            float o = (x - bm[k]) * (bg[k] * rsqrtf(bv[k] + 1e-5f)) + bb[k];
            houtb[(size_t)n * HD + k] = f2bf(o);
        }
    }
}

// ---------------- fused edge classifier: barrier-free MFMA pipeline ----------------
// Per-wave 16-edge tiles (grid-stride), edf prefetch, u gathers at tile top.
// Phase 5 via shuffle-reduce (no z2 LDS). LDS 22.5 KB; VGPR trimmed for 5 blocks/CU.

__global__ __launch_bounds__(256, 5) void edge_cls_k(
    const float* __restrict__ u1, const float* __restrict__ u2,
    const float* __restrict__ edf,
    const int* __restrict__ src, const int* __restrict__ dst,
    const short* __restrict__ WeTg, const float* __restrict__ be,
    const short* __restrict__ Wc1Tg, const float* __restrict__ bc1,
    const short* __restrict__ Wc2Tg, const float* __restrict__ bc2,
    const float* __restrict__ Wc3, const float* __restrict__ bc3,
    float* __restrict__ out, int E) {
    __shared__ short efA[4][16 * 136];   // per-wave ef bf16 [m][k], 17.4 KB
    __shared__ short z1A[4][16 * 40];    // per-wave z1 bf16, 5 KB

    int t = threadIdx.x;
    int w = t >> 6, lane = t & 63;
    int m = lane & 15, q = lane >> 4;
    short* efW = efA[w];
    short* z1W = z1A[w];

    int tiles = (E + 15) >> 4;
    int gw = blockIdx.x * 4 + w;
    int W  = gridDim.x * 4;

    float bc2m = bc2[m];
    float wc30 = Wc3[m * 2], wc31 = Wc3[m * 2 + 1];
    float bc30 = bc3[0], bc31 = bc3[1];

    auto ldrow = [&](int tl, float4& a, float4& b, float4& c, float4& d) {
        int em = tl * 16 + m;
        const float* rp = edf + (size_t)(em < E ? em : E - 1) * 64;
        a = *(const float4*)(rp + q * 8);
        b = *(const float4*)(rp + q * 8 + 4);
        c = *(const float4*)(rp + 32 + q * 8);
        d = *(const float4*)(rp + 32 + q * 8 + 4);
    };

    int tile = gw;
    float4 p0 = {0,0,0,0}, p1 = p0, p2 = p0, p3 = p0;
    if (tile < tiles) ldrow(tile, p0, p1, p2, p3);

    for (; tile < tiles; tile += W) {
        float4 c0 = p0, c1 = p1, c2 = p2, c3 = p3;
        int tn = tile + W;
        if (tn < tiles) ldrow(tn, p0, p1, p2, p3);   // edf prefetch (HBM)

        int e0w = tile * 16;

        // u1/u2 gathers issued at tile top, consumed in phase 3
        float u1g[2][4], u2g[2][4];
#pragma unroll
        for (int r = 0; r < 4; ++r) {
            int e = e0w + q * 4 + r;
            int ec = e < E ? e : E - 1;
            int s = src[ec], d = dst[ec];
            u1g[0][r] = u1[(size_t)s * 32 + m];
            u1g[1][r] = u1[(size_t)s * 32 + 16 + m];
            u2g[0][r] = u2[(size_t)d * 32 + m];
            u2g[1][r] = u2[(size_t)d * 32 + 16 + m];
        }

        short8 A0, A1;
        A0[0] = f2bf(c0.x); A0[1] = f2bf(c0.y); A0[2] = f2bf(c0.z); A0[3] = f2bf(c0.w);
        A0[4] = f2bf(c1.x); A0[5] = f2bf(c1.y); A0[6] = f2bf(c1.z); A0[7] = f2bf(c1.w);
        A1[0] = f2bf(c2.x); A1[1] = f2bf(c2.y); A1[2] = f2bf(c2.z); A1[3] = f2bf(c2.w);
        A1[4] = f2bf(c3.x); A1[5] = f2bf(c3.y); A1[6] = f2bf(c3.z); A1[7] = f2bf(c3.w);

        // ---- phase 2: ef = relu(ed@We+be) ----
#pragma unroll
        for (int nt = 0; nt < 8; ++nt) {
            int col = nt * 16 + m;
            float bias = be[col];
            f32x4 acc = {bias, bias, bias, bias};
            short8 b0 = *(const short8*)&WeTg[col * 64 + q * 8];
            short8 b1 = *(const short8*)&WeTg[col * 64 + 32 + q * 8];
            acc = __builtin_amdgcn_mfma_f32_16x16x32_bf16(A0, b0, acc, 0, 0, 0);
            acc = __builtin_amdgcn_mfma_f32_16x16x32_bf16(A1, b1, acc, 0, 0, 0);
#pragma unroll
            for (int r = 0; r < 4; ++r)
                efW[(q * 4 + r) * 136 + col] = f2bf(fmaxf(acc[r], 0.f));
        }
        lds_fence();

        // ---- phase 3: z1 = relu(ef@Wc1p + u1[src]+u2[dst]+bc1), stored bf16 A-ready ----
        short8 Az[4];
#pragma unroll
        for (int kt = 0; kt < 4; ++kt)
            Az[kt] = *(const short8*)&efW[m * 136 + kt * 32 + q * 8];
#pragma unroll
        for (int nt = 0; nt < 2; ++nt) {
            int col = nt * 16 + m;
            float bias = bc1[col];
            f32x4 acc = {bias, bias, bias, bias};
#pragma unroll
            for (int kt = 0; kt < 4; ++kt) {
                short8 b = *(const short8*)&Wc1Tg[col * 128 + kt * 32 + q * 8];
                acc = __builtin_amdgcn_mfma_f32_16x16x32_bf16(Az[kt], b, acc, 0, 0, 0);
            }
#pragma unroll
            for (int r = 0; r < 4; ++r) {
                float z = acc[r] + u1g[nt][r] + u2g[nt][r];
                z1W[(q * 4 + r) * 40 + col] = f2bf(fmaxf(z, 0.f));
            }
        }
        lds_fence();

        // ---- phase 4+5: z2 = relu(z1@Wc2+bc2) in regs; out via 16-lane shuffle reduce ----
        {
            short8 Az1 = *(const short8*)&z1W[m * 40 + q * 8];
            short8 Bz  = *(const short8*)&Wc2Tg[m * 32 + q * 8];
            f32x4 acc = {0.f, 0.f, 0.f, 0.f};
            acc = __builtin_amdgcn_mfma_f32_16x16x32_bf16(Az1, Bz, acc, 0, 0, 0);
            float a0[4], a1[4];
#pragma unroll
            for (int r = 0; r < 4; ++r) {
                float z = fmaxf(acc[r] + bc2m, 0.f);   // z2[edge=q*4+r][col=m]
                a0[r] = z * wc30;
                a1[r] = z * wc31;
            }
#pragma unroll
            for (int dd = 1; dd < 16; dd <<= 1) {
#pragma unroll
                for (int r = 0; r < 4; ++r) {
                    a0[r] += __shfl_xor(a0[r], dd, 64);
                    a1[r] += __shfl_xor(a1[r], dd, 64);
                }
            }
            if (m == 0) {
#pragma unroll
                for (int r = 0; r < 4; ++r) {
                    int eg = e0w + q * 4 + r;
                    if (eg < E) {
                        float2 o = {a0[r] + bc30, a1[r] + bc31};
                        *(float2*)&out[(size_t)eg * 2] = o;
                    }
                }
            }
        }
        lds_fence();   // Az/Az1 reads done before next tile overwrites efW/z1W
    }
}

// ---------------- launch ----------------

extern "C" void kernel_launch(void* const* d_in, const int* in_sizes, int n_in,
                              void* d_out, int out_size, void* d_ws, size_t ws_size,
                              hipStream_t stream) {
    const float* node_feats = (const float*)d_in[0];
    const float* edge_feats = (const float*)d_in[1];
    const int*   src  = (const int*)d_in[2];
    const int*   dst  = (const int*)d_in[3];
    const float* W0   = (const float*)d_in[4];
    const float* al0  = (const float*)d_in[5];
    const float* ar0  = (const float*)d_in[6];
    const float* b0   = (const float*)d_in[7];
    const float* g0   = (const float*)d_in[8];
    const float* bt0  = (const float*)d_in[9];
    const float* m0   = (const float*)d_in[10];
    const float* v0   = (const float*)d_in[11];
    const float* W1   = (const float*)d_in[12];
    const float* al1  = (const float*)d_in[13];
    const float* ar1  = (const float*)d_in[14];
    const float* b1   = (const float*)d_in[15];
    const float* Wr1  = (const float*)d_in[16];
    const float* g1   = (const float*)d_in[17];
    const float* bt1  = (const float*)d_in[18];
    const float* m1   = (const float*)d_in[19];
    const float* v1   = (const float*)d_in[20];
    const float* W2   = (const float*)d_in[21];
    const float* al2  = (const float*)d_in[22];
    const float* ar2  = (const float*)d_in[23];
    const float* b2   = (const float*)d_in[24];
    const float* Wr2  = (const float*)d_in[25];
    const float* g2   = (const float*)d_in[26];
    const float* bt2  = (const float*)d_in[27];
    const float* v2m  = (const float*)d_in[28];   // m2
    const float* v2v  = (const float*)d_in[29];   // v2
    const float* We   = (const float*)d_in[30];
    const float* be   = (const float*)d_in[31];
    const float* Wc1  = (const float*)d_in[32];
    const float* bc1  = (const float*)d_in[33];
    const float* Wc2  = (const float*)d_in[34];
    const float* bc2  = (const float*)d_in[35];
    const float* Wc3  = (const float*)d_in[36];
    const float* bc3  = (const float*)d_in[37];
    float* out = (float*)d_out;

    const int N = in_sizes[0] / 128;
    const int E = in_sizes[2];

    char* p = (char*)d_ws;
    auto alloc = [&](size_t bytes) -> void* {
        void* r = (void*)p;
        p += (bytes + 255) & ~(size_t)255;
        return r;
    };
    int*   deg   = (int*)alloc((size_t)N * 4);
    int*   off   = (int*)alloc((size_t)(N + 1) * 4);
    int*   rank  = (int*)alloc((size_t)E * 4);
    int*   srcp  = (int*)alloc((size_t)E * 4);
    int*   csum  = (int*)alloc(4096 * 4);
    short* featb = (short*)alloc((size_t)N * 128 * 2);
    short* h1b   = (short*)alloc((size_t)N * 128 * 2);
    short* h2b   = (short*)alloc((size_t)N * 64 * 2);
    short* h3b   = (short*)alloc((size_t)N * 32 * 2);
    float* resf  = (float*)alloc((size_t)N * 64 * 4);
    float* u1    = (float*)alloc((size_t)N * 32 * 4);
    float* u2    = (float*)alloc((size_t)N * 32 * 4);
    float* el    = (float*)alloc((size_t)N * 8 * 4);
    float* er    = (float*)alloc((size_t)N * 8 * 4);
    short* W0T   = (short*)alloc(128 * 128 * 2);
    short* W1T   = (short*)alloc(64 * 128 * 2);
    short* Wr1T  = (short*)alloc(64 * 128 * 2);
    short* W2T   = (short*)alloc(32 * 64 * 2);
    short* Wr2T  = (short*)alloc(32 * 64 * 2);
    short* Wc1aT = (short*)alloc(32 * 32 * 2);
    short* Wc1bT = (short*)alloc(32 * 32 * 2);
    short* WeTg  = (short*)alloc(128 * 64 * 2);
    short* Wc1Tg = (short*)alloc(32 * 128 * 2);
    short* Wc2Tg = (short*)alloc(16 * 32 * 2);

    hipMemsetAsync(deg, 0, (size_t)N * 4, stream);

    int eb = (E + 255) / 256;
    count_deg_k<<<eb, 256, 0, stream>>>(dst, deg, rank, E);
    scanA_k<<<16, 256, 0, stream>>>(deg, csum, N);
    scanB_k<<<1, 1024, 0, stream>>>(csum);
    scanC_k<<<16, 256, 0, stream>>>(deg, csum, off, N, E);
    scatter_k<<<eb, 256, 0, stream>>>(src, dst, off, rank, srcp, E);
    conv_w_k<<<202, 256, 0, stream>>>(W0, W1, Wr1, W2, Wr2, Wc1, We, Wc2,
                                      W0T, W1T, Wr1T, W2T, Wr2T,
                                      Wc1aT, Wc1bT, WeTg, Wc1Tg, Wc2Tg);

    int nb4 = (N + 3) / 4;
    int gtb = ((N + 15) / 16 + 3) / 4;

    // ---- Layer 0: 128 -> 8x16, identity residual, ELU, BN ----
    gemmM_k<128, 8, 0, true, true><<<gtb, 256, 0, stream>>>(node_feats, W0T, featb, nullptr, nullptr, N);
    elr_k<8, 16><<<(N * 8 + 255) / 256, 256, 0, stream>>>(featb, al0, ar0, el, er, N);
    gat_node3_k<8, 16, true><<<nb4, 256, 0, stream>>>(off, srcp, el, er, featb, node_feats,
                                                      b0, g0, bt0, m0, v0, h1b, N);
    // ---- Layer 1: 128 -> 8x8, projected residual, ELU, BN (dual MFMA GEMM) ----
    gemmM_k<128, 4, 4, true, false><<<gtb, 256, 0, stream>>>(h1b, W1T, featb, Wr1T, resf, N);
    elr_k<8, 8><<<(N * 8 + 255) / 256, 256, 0, stream>>>(featb, al1, ar1, el, er, N);
    gat_node3_k<8, 8, true><<<nb4, 256, 0, stream>>>(off, srcp, el, er, featb, resf,
                                                     b1, g1, bt1, m1, v1, h2b, N);
    // ---- Layer 2: 64 -> 1x32, projected residual, no act, BN (dual MFMA GEMM) ----
    gemmM_k<64, 2, 2, true, false><<<gtb, 256, 0, stream>>>(h2b, W2T, featb, Wr2T, resf, N);
    elr_k<1, 32><<<(N + 255) / 256, 256, 0, stream>>>(featb, al2, ar2, el, er, N);
    gat_node3_k<1, 32, false><<<nb4, 256, 0, stream>>>(off, srcp, el, er, featb, resf,
                                                       b2, g2, bt2, v2m, v2v, h3b, N);
    // ---- per-node halves of z1 (dual MFMA GEMM, f32 out) ----
    gemmM_k<32, 2, 2, false, false><<<gtb, 256, 0, stream>>>(h3b, Wc1aT, u1, Wc1bT, u2, N);
    // ---- fused edge classifier (single kernel, occupancy-tuned) ----
    int tiles = (E + 15) / 16;
    int blocks = (tiles + 15) / 16;      // 4 waves/block, 4 tiles/wave
    edge_cls_k<<<blocks, 256, 0, stream>>>(u1, u2, edge_feats, src, dst,
                                           WeTg, be, Wc1Tg, bc1,
                                           Wc2Tg, bc2, Wc3, bc3, out, E);
}

// Round 11
// 551.105 us; speedup vs baseline: 1.2385x; 1.2385x over previous
//
#include <hip/hip_runtime.h>
#include <cfloat>
#include <math.h>

#define NEG_SLOPE 0.2f

typedef short short8 __attribute__((ext_vector_type(8)));
typedef short short4v __attribute__((ext_vector_type(4)));
typedef float f32x4 __attribute__((ext_vector_type(4)));

__device__ __forceinline__ short f2bf(float x) {
    unsigned u = __float_as_uint(x);
    u += 0x7fffu + ((u >> 16) & 1u);
    return (short)(u >> 16);
}
__device__ __forceinline__ float bf2f(unsigned short s) {
    return __uint_as_float((unsigned)s << 16);
}

// wave-local LDS fence (buffers are wave-private; no block barrier needed)
__device__ __forceinline__ void lds_fence() {
    __asm__ __volatile__("s_waitcnt lgkmcnt(0)" ::: "memory");
}

// ---------------- CSR construction ----------------

__global__ void count_deg_k(const int* __restrict__ dst, int* __restrict__ deg,
                            int* __restrict__ rank, int E) {
    int i = blockIdx.x * 256 + threadIdx.x;
    if (i < E) rank[i] = atomicAdd(&deg[dst[i]], 1);
}

// parallel scan: A) 4096 chunk sums  B) scan chunk sums  C) write offsets
__global__ void scanA_k(const int* __restrict__ deg, int* __restrict__ csum, int n) {
    int t = blockIdx.x * 256 + threadIdx.x;   // t < 4096
    int ch = (n + 4095) >> 12;
    int beg = t * ch, end = min(beg + ch, n);
    int s = 0;
    for (int i = beg; i < end; ++i) s += deg[i];
    csum[t] = s;
}

__global__ void scanB_k(int* __restrict__ csum) {
    __shared__ int part[1024];
    int tid = threadIdx.x;
    int c[4];
    int s = 0;
#pragma unroll
    for (int i = 0; i < 4; ++i) { c[i] = csum[tid * 4 + i]; s += c[i]; }
    part[tid] = s;
    __syncthreads();
    for (int d = 1; d < 1024; d <<= 1) {
        int v = (tid >= d) ? part[tid - d] : 0;
        __syncthreads();
        part[tid] += v;
        __syncthreads();
    }
    int base = (tid > 0) ? part[tid - 1] : 0;
#pragma unroll
    for (int i = 0; i < 4; ++i) { csum[tid * 4 + i] = base; base += c[i]; }
}

__global__ void scanC_k(const int* __restrict__ deg, const int* __restrict__ csum,
                        int* __restrict__ off, int n, int E) {
    int t = blockIdx.x * 256 + threadIdx.x;   // t < 4096
    int ch = (n + 4095) >> 12;
    int beg = t * ch, end = min(beg + ch, n);
    int run = csum[t];
    for (int i = beg; i < end; ++i) { off[i] = run; run += deg[i]; }
    if (t == 0) off[n] = E;
}

__global__ void scatter_k(const int* __restrict__ src, const int* __restrict__ dst,
                          const int* __restrict__ off, const int* __restrict__ rank,
                          int* __restrict__ srcp, int E) {
    int i = blockIdx.x * 256 + threadIdx.x;
    if (i >= E) return;
    srcp[off[dst[i]] + rank[i]] = src[i];
}

// ---------------- bf16 weight precompute: BT[n*K+k] = B[k*OUT+n] ----------------

__global__ void conv_w_k(const float* W0, const float* W1, const float* Wr1,
                         const float* W2, const float* Wr2, const float* Wc1,
                         const float* We, const float* Wc2,
                         short* W0T, short* W1T, short* Wr1T, short* W2T, short* Wr2T,
                         short* Wc1aT, short* Wc1bT, short* WeT, short* Wc1T, short* Wc2T) {
    int t = blockIdx.x * 256 + threadIdx.x;
    const float* src; short* dst; int K, OUT, base;
    if      (t < 16384) { src = W0;            dst = W0T;   K = 128; OUT = 128; base = 0; }
    else if (t < 24576) { src = W1;            dst = W1T;   K = 128; OUT = 64;  base = 16384; }
    else if (t < 32768) { src = Wr1;           dst = Wr1T;  K = 128; OUT = 64;  base = 24576; }
    else if (t < 34816) { src = W2;            dst = W2T;   K = 64;  OUT = 32;  base = 32768; }
    else if (t < 36864) { src = Wr2;           dst = Wr2T;  K = 64;  OUT = 32;  base = 34816; }
    else if (t < 37888) { src = Wc1;           dst = Wc1aT; K = 32;  OUT = 32;  base = 36864; }
    else if (t < 38912) { src = Wc1 + 1024;    dst = Wc1bT; K = 32;  OUT = 32;  base = 37888; }
    else if (t < 47104) { src = We;            dst = WeT;   K = 64;  OUT = 128; base = 38912; }
    else if (t < 51200) { src = Wc1 + 64 * 32; dst = Wc1T;  K = 128; OUT = 32;  base = 47104; }
    else if (t < 51712) { src = Wc2;           dst = Wc2T;  K = 32;  OUT = 16;  base = 51200; }
    else return;
    int local = t - base;
    int k = local / OUT, n = local % OUT;
    dst[n * K + k] = f2bf(src[k * OUT + n]);
}

// ---------------- per-wave MFMA GEMM: 16 rows/wave, dual fused outputs ----------------

template<int K, int NT1, int NT2, bool C1B16, bool AF32>
__global__ __launch_bounds__(256) void gemmM_k(const void* __restrict__ A,
                                               const short* __restrict__ B1T, void* __restrict__ C1,
                                               const short* __restrict__ B2T, float* __restrict__ C2,
                                               int N) {
    int w = threadIdx.x >> 6, lane = threadIdx.x & 63;
    int tile = blockIdx.x * 4 + w;
    int row0 = tile * 16;
    if (row0 >= N) return;
    int m = lane & 15, q = lane >> 4;
    int arow = row0 + m; if (arow >= N) arow = N - 1;

    constexpr int KT = K / 32;
    short8 Af[KT];
    if constexpr (AF32) {
        const float* Ap = (const float*)A + (size_t)arow * K;
#pragma unroll
        for (int kt = 0; kt < KT; ++kt) {
            float4 x = *(const float4*)&Ap[kt * 32 + q * 8];
            float4 y = *(const float4*)&Ap[kt * 32 + q * 8 + 4];
            short8 s;
            s[0] = f2bf(x.x); s[1] = f2bf(x.y); s[2] = f2bf(x.z); s[3] = f2bf(x.w);
            s[4] = f2bf(y.x); s[5] = f2bf(y.y); s[6] = f2bf(y.z); s[7] = f2bf(y.w);
            Af[kt] = s;
        }
    } else {
        const short* Ap = (const short*)A + (size_t)arow * K;
#pragma unroll
        for (int kt = 0; kt < KT; ++kt)
            Af[kt] = *(const short8*)&Ap[kt * 32 + q * 8];
    }

#pragma unroll
    for (int nt = 0; nt < NT1; ++nt) {
        f32x4 acc = {0.f, 0.f, 0.f, 0.f};
#pragma unroll
        for (int kt = 0; kt < KT; ++kt) {
            short8 b = *(const short8*)&B1T[(size_t)(nt * 16 + m) * K + kt * 32 + q * 8];
            acc = __builtin_amdgcn_mfma_f32_16x16x32_bf16(Af[kt], b, acc, 0, 0, 0);
        }
#pragma unroll
        for (int r = 0; r < 4; ++r) {
            int row = row0 + q * 4 + r;
            if (row < N) {
                if constexpr (C1B16)
                    ((short*)C1)[(size_t)row * (NT1 * 16) + nt * 16 + m] = f2bf(acc[r]);
                else
                    ((float*)C1)[(size_t)row * (NT1 * 16) + nt * 16 + m] = acc[r];
            }
        }
    }
    if constexpr (NT2 > 0) {
#pragma unroll
        for (int nt = 0; nt < NT2; ++nt) {
            f32x4 acc = {0.f, 0.f, 0.f, 0.f};
#pragma unroll
            for (int kt = 0; kt < KT; ++kt) {
                short8 b = *(const short8*)&B2T[(size_t)(nt * 16 + m) * K + kt * 32 + q * 8];
                acc = __builtin_amdgcn_mfma_f32_16x16x32_bf16(Af[kt], b, acc, 0, 0, 0);
            }
#pragma unroll
            for (int r = 0; r < 4; ++r) {
                int row = row0 + q * 4 + r;
                if (row < N)
                    C2[(size_t)row * (NT2 * 16) + nt * 16 + m] = acc[r];
            }
        }
    }
}

// ---------------- attention logits (from bf16 feat) ----------------

template<int H, int D>
__global__ void elr_k(const short* __restrict__ featb, const float* __restrict__ al,
                      const float* __restrict__ ar, float* __restrict__ el,
                      float* __restrict__ er, int n) {
    int i = blockIdx.x * 256 + threadIdx.x;
    if (i >= n * H) return;
    int h = i % H;
    const short* f = featb + (size_t)(i / H) * (H * D) + h * D;
    float sl = 0.f, sr = 0.f;
#pragma unroll
    for (int d = 0; d < D; ++d) {
        float v = bf2f((unsigned short)f[d]);
        sl = fmaf(v, al[h * D + d], sl);
        sr = fmaf(v, ar[h * D + d], sr);
    }
    el[i] = sl; er[i] = sr;
}

// ---- GAT node stage: wave-per-node, single sweep, no-max softmax, staged bf16 gathers ----

template<int H, int D, bool ACT>
__global__ __launch_bounds__(256) void gat_node3_k(
    const int* __restrict__ off, const int* __restrict__ srcp,
    const float* __restrict__ el, const float* __restrict__ er,
    const short* __restrict__ featb,
    const float* __restrict__ res, const float* __restrict__ bias,
    const float* __restrict__ bg, const float* __restrict__ bb,
    const float* __restrict__ bm, const float* __restrict__ bv,
    short* __restrict__ houtb, int N) {
    constexpr int HD = H * D;
    constexpr bool PAIR = (HD > 64);
    constexpr int CH = 64 / H;
    constexpr int SB = (CH < 8) ? CH : 8;
    int wv_ = threadIdx.x >> 6;
    int lane = threadIdx.x & 63;
    int n = blockIdx.x * 4 + wv_;
    if (n >= N) return;
    int beg = off[n], end = off[n + 1];

    int hh = lane % H;
    int cc = lane / H;
    float ern = er[(size_t)n * H + hh];

    int k0 = PAIR ? 2 * lane : lane;
    int h0 = k0 / D; if (h0 > H - 1) h0 = H - 1;

    float acc0 = 0.f, acc1 = 0.f, svp = 0.f;

    for (int i0 = beg; i0 < end; i0 += CH) {
        int iw = i0 + cc;
        float wv = 0.f;
        int sidx = 0;
        if (iw < end) {
            sidx = srcp[iw];
            float x = el[(size_t)sidx * H + hh] + ern;
            x = x > 0.f ? x : NEG_SLOPE * x;
            wv = __expf(x);                  // no max-sub: |x| is O(1) by construction
        }
        svp += wv;
        int lim = min(end - i0, CH);
        for (int rb = 0; rb < lim; rb += SB) {
            int bs = lim - rb; if (bs > SB) bs = SB;
            float ws[SB]; int ss[SB];
#pragma unroll
            for (int j = 0; j < SB; ++j) {
                int sl = (rb + j) * H + h0;
                ws[j] = __shfl(wv, sl, 64);
                ss[j] = __shfl(sidx, sl, 64);
            }
            if constexpr (PAIR) {
                unsigned rows[SB];
#pragma unroll
                for (int j = 0; j < SB; ++j)
                    if (j < bs) rows[j] = *(const unsigned*)&featb[(size_t)ss[j] * HD + k0];
#pragma unroll
                for (int j = 0; j < SB; ++j)
                    if (j < bs) {
                        acc0 = fmaf(ws[j], bf2f((unsigned short)(rows[j] & 0xffffu)), acc0);
                        acc1 = fmaf(ws[j], bf2f((unsigned short)(rows[j] >> 16)), acc1);
                    }
            } else {
                unsigned short rows[SB];
#pragma unroll
                for (int j = 0; j < SB; ++j)
                    if (j < bs && lane < HD)
                        rows[j] = (unsigned short)featb[(size_t)ss[j] * HD + k0];
#pragma unroll
                for (int j = 0; j < SB; ++j)
                    if (j < bs && lane < HD)
                        acc0 = fmaf(ws[j], bf2f(rows[j]), acc0);
            }
        }
    }
#pragma unroll
    for (int mm = H; mm < 64; mm <<= 1) svp += __shfl_xor(svp, mm, 64);
    bool has_edges = end > beg;
    float inv0 = has_edges ? 1.f / __shfl(svp, h0, 64) : 0.f;

    if constexpr (PAIR) {
        float2 rs = *(const float2*)&res[(size_t)n * HD + k0];
        float2 bi = *(const float2*)&bias[k0];
        float2 gm = *(const float2*)&bm[k0];
        float2 gv = *(const float2*)&bv[k0];
        float2 gg = *(const float2*)&bg[k0];
        float2 gb = *(const float2*)&bb[k0];
        float x0 = acc0 * inv0 + rs.x + bi.x;
        float x1 = acc1 * inv0 + rs.y + bi.y;
        if (ACT) { x0 = x0 > 0.f ? x0 : expm1f(x0); x1 = x1 > 0.f ? x1 : expm1f(x1); }
        float o0 = (x0 - gm.x) * (gg.x * rsqrtf(gv.x + 1e-5f)) + gb.x;
        float o1 = (x1 - gm.y) * (gg.y * rsqrtf(gv.y + 1e-5f)) + gb.y;
        ushort2 hb;
        hb.x = (unsigned short)f2bf(o0);
        hb.y = (unsigned short)f2bf(o1);
        *(ushort2*)&houtb[(size_t)n * HD + k0] = hb;
    } else {
        if (lane < HD) {
            int k = k0;
            float x = acc0 * inv0 + res[(size_t)n * HD + k] + bias[k];
            if (ACT) x = x > 0.f ? x : expm1f(x);
            float o = (x - bm[k]) * (bg[k] * rsqrtf(bv[k] + 1e-5f)) + bb[k];
            houtb[(size_t)n * HD + k] = f2bf(o);
        }
    }
}

// ---------------- fused edge classifier: barrier-free MFMA pipeline ----------------
// Per-wave 16-edge tiles (grid-stride), edf prefetch, u gathers at tile top.
// Phase 5 via shuffle-reduce (no z2 LDS). NOTE: no waves/EU bound — forcing
// occupancy below the natural ~110-VGPR allocation spills the prefetch state
// to scratch (R10: FETCH 118->480 MB, dur 88->236 us).

__global__ __launch_bounds__(256) void edge_cls_k(
    const float* __restrict__ u1, const float* __restrict__ u2,
    const float* __restrict__ edf,
    const int* __restrict__ src, const int* __restrict__ dst,
    const short* __restrict__ WeTg, const float* __restrict__ be,
    const short* __restrict__ Wc1Tg, const float* __restrict__ bc1,
    const short* __restrict__ Wc2Tg, const float* __restrict__ bc2,
    const float* __restrict__ Wc3, const float* __restrict__ bc3,
    float* __restrict__ out, int E) {
    __shared__ short efA[4][16 * 136];   // per-wave ef bf16 [m][k], 17.4 KB
    __shared__ short z1A[4][16 * 40];    // per-wave z1 bf16, 5 KB

    int t = threadIdx.x;
    int w = t >> 6, lane = t & 63;
    int m = lane & 15, q = lane >> 4;
    short* efW = efA[w];
    short* z1W = z1A[w];

    int tiles = (E + 15) >> 4;
    int gw = blockIdx.x * 4 + w;
    int W  = gridDim.x * 4;

    float bc2m = bc2[m];
    float wc30 = Wc3[m * 2], wc31 = Wc3[m * 2 + 1];
    float bc30 = bc3[0], bc31 = bc3[1];

    auto ldrow = [&](int tl, float4& a, float4& b, float4& c, float4& d) {
        int em = tl * 16 + m;
        const float* rp = edf + (size_t)(em < E ? em : E - 1) * 64;
        a = *(const float4*)(rp + q * 8);
        b = *(const float4*)(rp + q * 8 + 4);
        c = *(const float4*)(rp + 32 + q * 8);
        d = *(const float4*)(rp + 32 + q * 8 + 4);
    };

    int tile = gw;
    float4 p0 = {0,0,0,0}, p1 = p0, p2 = p0, p3 = p0;
    if (tile < tiles) ldrow(tile, p0, p1, p2, p3);

    for (; tile < tiles; tile += W) {
        float4 c0 = p0, c1 = p1, c2 = p2, c3 = p3;
        int tn = tile + W;
        if (tn < tiles) ldrow(tn, p0, p1, p2, p3);   // edf prefetch (HBM)

        int e0w = tile * 16;

        // u1/u2 gathers issued at tile top, consumed in phase 3
        float u1g[2][4], u2g[2][4];
#pragma unroll
        for (int r = 0; r < 4; ++r) {
            int e = e0w + q * 4 + r;
            int ec = e < E ? e : E - 1;
            int s = src[ec], d = dst[ec];
            u1g[0][r] = u1[(size_t)s * 32 + m];
            u1g[1][r] = u1[(size_t)s * 32 + 16 + m];
            u2g[0][r] = u2[(size_t)d * 32 + m];
            u2g[1][r] = u2[(size_t)d * 32 + 16 + m];
        }

        short8 A0, A1;
        A0[0] = f2bf(c0.x); A0[1] = f2bf(c0.y); A0[2] = f2bf(c0.z); A0[3] = f2bf(c0.w);
        A0[4] = f2bf(c1.x); A0[5] = f2bf(c1.y); A0[6] = f2bf(c1.z); A0[7] = f2bf(c1.w);
        A1[0] = f2bf(c2.x); A1[1] = f2bf(c2.y); A1[2] = f2bf(c2.z); A1[3] = f2bf(c2.w);
        A1[4] = f2bf(c3.x); A1[5] = f2bf(c3.y); A1[6] = f2bf(c3.z); A1[7] = f2bf(c3.w);

        // ---- phase 2: ef = relu(ed@We+be) ----
#pragma unroll
        for (int nt = 0; nt < 8; ++nt) {
            int col = nt * 16 + m;
            float bias = be[col];
            f32x4 acc = {bias, bias, bias, bias};
            short8 b0 = *(const short8*)&WeTg[col * 64 + q * 8];
            short8 b1 = *(const short8*)&WeTg[col * 64 + 32 + q * 8];
            acc = __builtin_amdgcn_mfma_f32_16x16x32_bf16(A0, b0, acc, 0, 0, 0);
            acc = __builtin_amdgcn_mfma_f32_16x16x32_bf16(A1, b1, acc, 0, 0, 0);
#pragma unroll
            for (int r = 0; r < 4; ++r)
                efW[(q * 4 + r) * 136 + col] = f2bf(fmaxf(acc[r], 0.f));
        }
        lds_fence();

        // ---- phase 3: z1 = relu(ef@Wc1p + u1[src]+u2[dst]+bc1), stored bf16 A-ready ----
        short8 Az[4];
#pragma unroll
        for (int kt = 0; kt < 4; ++kt)
            Az[kt] = *(const short8*)&efW[m * 136 + kt * 32 + q * 8];
#pragma unroll
        for (int nt = 0; nt < 2; ++nt) {
            int col = nt * 16 + m;
            float bias = bc1[col];
            f32x4 acc = {bias, bias, bias, bias};
#pragma unroll
            for (int kt = 0; kt < 4; ++kt) {
                short8 b = *(const short8*)&Wc1Tg[col * 128 + kt * 32 + q * 8];
                acc = __builtin_amdgcn_mfma_f32_16x16x32_bf16(Az[kt], b, acc, 0, 0, 0);
            }
#pragma unroll
            for (int r = 0; r < 4; ++r) {
                float z = acc[r] + u1g[nt][r] + u2g[nt][r];
                z1W[(q * 4 + r) * 40 + col] = f2bf(fmaxf(z, 0.f));
            }
        }
        lds_fence();

        // ---- phase 4+5: z2 = relu(z1@Wc2+bc2) in regs; out via 16-lane shuffle reduce ----
        {
            short8 Az1 = *(const short8*)&z1W[m * 40 + q * 8];
            short8 Bz  = *(const short8*)&Wc2Tg[m * 32 + q * 8];
            f32x4 acc = {0.f, 0.f, 0.f, 0.f};
            acc = __builtin_amdgcn_mfma_f32_16x16x32_bf16(Az1, Bz, acc, 0, 0, 0);
            float a0[4], a1[4];
#pragma unroll
            for (int r = 0; r < 4; ++r) {
                float z = fmaxf(acc[r] + bc2m, 0.f);   // z2[edge=q*4+r][col=m]
                a0[r] = z * wc30;
                a1[r] = z * wc31;
            }
#pragma unroll
            for (int dd = 1; dd < 16; dd <<= 1) {
#pragma unroll
                for (int r = 0; r < 4; ++r) {
                    a0[r] += __shfl_xor(a0[r], dd, 64);
                    a1[r] += __shfl_xor(a1[r], dd, 64);
                }
            }
            if (m == 0) {
#pragma unroll
                for (int r = 0; r < 4; ++r) {
                    int eg = e0w + q * 4 + r;
                    if (eg < E) {
                        float2 o = {a0[r] + bc30, a1[r] + bc31};
                        *(float2*)&out[(size_t)eg * 2] = o;
                    }
                }
            }
        }
        lds_fence();   // Az/Az1 reads done before next tile overwrites efW/z1W
    }
}

// ---------------- launch ----------------

extern "C" void kernel_launch(void* const* d_in, const int* in_sizes, int n_in,
                              void* d_out, int out_size, void* d_ws, size_t ws_size,
                              hipStream_t stream) {
    const float* node_feats = (const float*)d_in[0];
    const float* edge_feats = (const float*)d_in[1];
    const int*   src  = (const int*)d_in[2];
    const int*   dst  = (const int*)d_in[3];
    const float* W0   = (const float*)d_in[4];
    const float* al0  = (const float*)d_in[5];
    const float* ar0  = (const float*)d_in[6];
    const float* b0   = (const float*)d_in[7];
    const float* g0   = (const float*)d_in[8];
    const float* bt0  = (const float*)d_in[9];
    const float* m0   = (const float*)d_in[10];
    const float* v0   = (const float*)d_in[11];
    const float* W1   = (const float*)d_in[12];
    const float* al1  = (const float*)d_in[13];
    const float* ar1  = (const float*)d_in[14];
    const float* b1   = (const float*)d_in[15];
    const float* Wr1  = (const float*)d_in[16];
    const float* g1   = (const float*)d_in[17];
    const float* bt1  = (const float*)d_in[18];
    const float* m1   = (const float*)d_in[19];
    const float* v1   = (const float*)d_in[20];
    const float* W2   = (const float*)d_in[21];
    const float* al2  = (const float*)d_in[22];
    const float* ar2  = (const float*)d_in[23];
    const float* b2   = (const float*)d_in[24];
    const float* Wr2  = (const float*)d_in[25];
    const float* g2   = (const float*)d_in[26];
    const float* bt2  = (const float*)d_in[27];
    const float* v2m  = (const float*)d_in[28];   // m2
    const float* v2v  = (const float*)d_in[29];   // v2
    const float* We   = (const float*)d_in[30];
    const float* be   = (const float*)d_in[31];
    const float* Wc1  = (const float*)d_in[32];
    const float* bc1  = (const float*)d_in[33];
    const float* Wc2  = (const float*)d_in[34];
    const float* bc2  = (const float*)d_in[35];
    const float* Wc3  = (const float*)d_in[36];
    const float* bc3  = (const float*)d_in[37];
    float* out = (float*)d_out;

    const int N = in_sizes[0] / 128;
    const int E = in_sizes[2];

    char* p = (char*)d_ws;
    auto alloc = [&](size_t bytes) -> void* {
        void* r = (void*)p;
        p += (bytes + 255) & ~(size_t)255;
        return r;
    };
    int*   deg   = (int*)alloc((size_t)N * 4);
    int*   off   = (int*)alloc((size_t)(N + 1) * 4);
    int*   rank  = (int*)alloc((size_t)E * 4);
    int*   srcp  = (int*)alloc((size_t)E * 4);
    int*   csum  = (int*)alloc(4096 * 4);
    short* featb = (short*)alloc((size_t)N * 128 * 2);
    short* h1b   = (short*)alloc((size_t)N * 128 * 2);
    short* h2b   = (short*)alloc((size_t)N * 64 * 2);
    short* h3b   = (short*)alloc((size_t)N * 32 * 2);
    float* resf  = (float*)alloc((size_t)N * 64 * 4);
    float* u1    = (float*)alloc((size_t)N * 32 * 4);
    float* u2    = (float*)alloc((size_t)N * 32 * 4);
    float* el    = (float*)alloc((size_t)N * 8 * 4);
    float* er    = (float*)alloc((size_t)N * 8 * 4);
    short* W0T   = (short*)alloc(128 * 128 * 2);
    short* W1T   = (short*)alloc(64 * 128 * 2);
    short* Wr1T  = (short*)alloc(64 * 128 * 2);
    short* W2T   = (short*)alloc(32 * 64 * 2);
    short* Wr2T  = (short*)alloc(32 * 64 * 2);
    short* Wc1aT = (short*)alloc(32 * 32 * 2);
    short* Wc1bT = (short*)alloc(32 * 32 * 2);
    short* WeTg  = (short*)alloc(128 * 64 * 2);
    short* Wc1Tg = (short*)alloc(32 * 128 * 2);
    short* Wc2Tg = (short*)alloc(16 * 32 * 2);

    hipMemsetAsync(deg, 0, (size_t)N * 4, stream);

    int eb = (E + 255) / 256;
    count_deg_k<<<eb, 256, 0, stream>>>(dst, deg, rank, E);
    scanA_k<<<16, 256, 0, stream>>>(deg, csum, N);
    scanB_k<<<1, 1024, 0, stream>>>(csum);
    scanC_k<<<16, 256, 0, stream>>>(deg, csum, off, N, E);
    scatter_k<<<eb, 256, 0, stream>>>(src, dst, off, rank, srcp, E);
    conv_w_k<<<202, 256, 0, stream>>>(W0, W1, Wr1, W2, Wr2, Wc1, We, Wc2,
                                      W0T, W1T, Wr1T, W2T, Wr2T,
                                      Wc1aT, Wc1bT, WeTg, Wc1Tg, Wc2Tg);

    int nb4 = (N + 3) / 4;
    int gtb = ((N + 15) / 16 + 3) / 4;

    // ---- Layer 0: 128 -> 8x16, identity residual, ELU, BN ----
    gemmM_k<128, 8, 0, true, true><<<gtb, 256, 0, stream>>>(node_feats, W0T, featb, nullptr, nullptr, N);
    elr_k<8, 16><<<(N * 8 + 255) / 256, 256, 0, stream>>>(featb, al0, ar0, el, er, N);
    gat_node3_k<8, 16, true><<<nb4, 256, 0, stream>>>(off, srcp, el, er, featb, node_feats,
                                                      b0, g0, bt0, m0, v0, h1b, N);
    // ---- Layer 1: 128 -> 8x8, projected residual, ELU, BN (dual MFMA GEMM) ----
    gemmM_k<128, 4, 4, true, false><<<gtb, 256, 0, stream>>>(h1b, W1T, featb, Wr1T, resf, N);
    elr_k<8, 8><<<(N * 8 + 255) / 256, 256, 0, stream>>>(featb, al1, ar1, el, er, N);
    gat_node3_k<8, 8, true><<<nb4, 256, 0, stream>>>(off, srcp, el, er, featb, resf,
                                                     b1, g1, bt1, m1, v1, h2b, N);
    // ---- Layer 2: 64 -> 1x32, projected residual, no act, BN (dual MFMA GEMM) ----
    gemmM_k<64, 2, 2, true, false><<<gtb, 256, 0, stream>>>(h2b, W2T, featb, Wr2T, resf, N);
    elr_k<1, 32><<<(N + 255) / 256, 256, 0, stream>>>(featb, al2, ar2, el, er, N);
    gat_node3_k<1, 32, false><<<nb4, 256, 0, stream>>>(off, srcp, el, er, featb, resf,
                                                       b2, g2, bt2, v2m, v2v, h3b, N);
    // ---- per-node halves of z1 (dual MFMA GEMM, f32 out) ----
    gemmM_k<32, 2, 2, false, false><<<gtb, 256, 0, stream>>>(h3b, Wc1aT, u1, Wc1bT, u2, N);
    // ---- fused edge classifier (single kernel) ----
    int tiles = (E + 15) / 16;
    int blocks = (tiles + 15) / 16;      // 4 waves/block, 4 tiles/wave
    edge_cls_k<<<blocks, 256, 0, stream>>>(u1, u2, edge_feats, src, dst,
                                           WeTg, be, Wc1Tg, bc1,
                                           Wc2Tg, bc2, Wc3, bc3, out, E);
}